// Round 11
// baseline (15.446 us; speedup 1.0000x reference)
//
#include <hip/hip_runtime.h>

typedef float f32x4 __attribute__((ext_vector_type(4)));

#define BLOCK 256   // 4 waves per block, one anchor per wave

// Fused triplet miner: ONE WAVE per anchor, minimized serial chain.
//  - lane reads 8 CONTIGUOUS labels (2x int4 at chunks kbase+2*lane, +1),
//    512 labels/iteration, 2-deep register prefetch.
//  - per iteration: 8 compares -> 8-bit mask -> TWO ballots -> branch.
//  - match masks captured at ballot time; post-loop resolve is shfl+ffs
//    (no reloads on the critical chain).
//  - anchor emb row loaded BEFORE mining (latency hidden under the scan);
//    pos+neg rows fetched with one combined instruction afterwards.
//  - NORMAL stores (through L2): L2 write-combines the 25 MB stream into
//    full lines; NT direct-to-HBM 16B stores were the suspected 2x loss.
__global__ void __launch_bounds__(BLOCK) triplet_fused_kernel(
    const int* __restrict__ labels,
    const f32x4* __restrict__ emb,    // [N][32]
    f32x4* __restrict__ out,          // [3][N][32]
    float* __restrict__ valid_out,    // [N]
    int N) {

    const int D4 = 32;
    int lane = threadIdx.x & 63;
    int i = blockIdx.x * (BLOCK >> 6) + (threadIdx.x >> 6);   // anchor (wave-uniform)
    if (i >= N) return;

    // Early independent loads: anchor label + anchor embedding row.
    int d4 = lane & 31;
    f32x4 ea = emb[(size_t)i * D4 + d4];   // row i (L1 broadcast across lanes)
    int my = labels[i];

    const int4* lab4 = (const int4*)labels;
    int nq = N >> 2;                       // N % 4 == 0

    int kb0 = (i + 1) >> 2;                // first chunk containing j > i

    // First-iteration validity mask: only lane 0's first chunk can hold j <= i.
    unsigned mv_first = 0xFFu;
    if (lane == 0) {
        int j0 = kb0 << 2;
        int nclr = i - j0 + 1;             // leading labels with j <= i (0..3)
        if (nclr > 0) mv_first &= (0xFFu << nclr);
    }

    int kbase = kb0;
    bool fp = false, fn = false;
    unsigned long long balp = 0, baln = 0;
    int basep = 0, basen = 0;
    unsigned msp = 0, msn = 0;             // captured masked match masks

    // 2-deep prefetch (clamped addresses; masked by mv in processing).
    int4 a0 = lab4[min(kbase + 2 * lane,     nq - 1)];
    int4 b0 = lab4[min(kbase + 2 * lane + 1, nq - 1)];
    int4 a1 = lab4[min(kbase + 128 + 2 * lane,     nq - 1)];
    int4 b1 = lab4[min(kbase + 128 + 2 * lane + 1, nq - 1)];

    unsigned mv_iter = mv_first;
    if (kbase < nq) {
        while (true) {
            int4 a2 = lab4[min(kbase + 256 + 2 * lane,     nq - 1)];
            int4 b2 = lab4[min(kbase + 256 + 2 * lane + 1, nq - 1)];

            int kq0 = kbase + 2 * lane, kq1 = kq0 + 1;
            unsigned mv = mv_iter;
            if (kq0 >= nq)      mv = 0;
            else if (kq1 >= nq) mv &= 0x0Fu;

            unsigned ms = (a0.x == my ?   1u : 0u) | (a0.y == my ?   2u : 0u)
                        | (a0.z == my ?   4u : 0u) | (a0.w == my ?   8u : 0u)
                        | (b0.x == my ?  16u : 0u) | (b0.y == my ?  32u : 0u)
                        | (b0.z == my ?  64u : 0u) | (b0.w == my ? 128u : 0u);

            unsigned mp = ms & mv;
            unsigned mn = (~ms) & mv;
            unsigned long long bp = __ballot(mp != 0u);
            unsigned long long bn = __ballot(mn != 0u);
            if (!fp && bp) { fp = true; balp = bp; basep = kbase; msp = mp; }
            if (!fn && bn) { fn = true; baln = bn; basen = kbase; msn = mn; }

            kbase += 128;
            if ((fp && fn) || kbase >= nq) break;
            a0 = a1; b0 = b1; a1 = a2; b1 = b2;
            mv_iter = 0xFFu;
        }
    }

    // Resolve exact indices: pure ALU + shfl (no memory on the chain).
    int p = 0, ng = 0;
    if (fp) {
        int ls = (int)__ffsll(balp) - 1;
        unsigned m = __shfl(msp, ls);
        p = ((basep + 2 * ls) << 2) + (__ffs(m) - 1);
    }
    if (fn) {
        int ls = (int)__ffsll(baln) - 1;
        unsigned m = __shfl(msn, ls);
        ng = ((basen + 2 * ls) << 2) + (__ffs(m) - 1);
    }

    float v = (fp && fn) ? 1.0f : 0.0f;

    // Combined gather: lanes<32 -> neg row, lanes>=32 -> pos row (one instr).
    size_t ND4 = (size_t)N * D4;
    int gsrc = (lane < 32) ? ng : p;
    f32x4 eg = emb[(size_t)gsrc * D4 + d4];

    if (lane == 0) valid_out[i] = v;

    // Pass 1: lanes<32 store anchor row (t=0), lanes>=32 store pos row (t=1).
    int   t  = lane >> 5;
    f32x4 r0 = (lane < 32) ? ea : eg;
    out[(size_t)t * ND4 + (size_t)i * D4 + d4] = r0 * v;

    // Pass 2: lanes<32 store neg row (t=2).
    if (lane < 32)
        out[2 * ND4 + (size_t)i * D4 + d4] = eg * v;
}

extern "C" void kernel_launch(void* const* d_in, const int* in_sizes, int n_in,
                              void* d_out, int out_size, void* d_ws, size_t ws_size,
                              hipStream_t stream) {
    const float* emb    = (const float*)d_in[0];
    const int*   labels = (const int*)d_in[1];   // harness passes integers as int32

    int N = in_sizes[1];             // 16384
    int D = in_sizes[0] / N;         // 128 (D4 = 32 hard-wired in kernel)

    float* out       = (float*)d_out;
    float* valid_out = out + (size_t)3 * N * D;  // tail of d_out: [N] valid mask

    int nblk = (N * 64 + BLOCK - 1) / BLOCK;     // one wave per anchor
    triplet_fused_kernel<<<nblk, BLOCK, 0, stream>>>(
        labels, (const f32x4*)emb, (f32x4*)out, valid_out, N);
}

// Round 12
// 15.333 us; speedup vs baseline: 1.0074x; 1.0074x over previous
//
#include <hip/hip_runtime.h>

typedef float f32x4 __attribute__((ext_vector_type(4)));

#define BLOCK 256   // 4 waves per block, one anchor per wave

// Fused triplet miner: ONE WAVE per anchor, minimized serial chain.
//  - lane reads 8 CONTIGUOUS labels (2x int4 at chunks kbase+2*lane, +1),
//    512 labels/iteration, 2-deep register prefetch.
//  - per iteration: 8 compares -> 8-bit mask -> TWO ballots -> branch.
//  - match masks captured at ballot time; post-loop resolve is shfl+ffs
//    (no reloads on the critical chain).
//  - anchor emb row loaded BEFORE mining (latency hidden under the scan);
//    pos+neg rows fetched with one combined instruction afterwards.
//  - NORMAL stores (through L2): L2 write-combines the 25 MB stream into
//    full lines; NT direct-to-HBM 16B stores were the suspected 2x loss.
__global__ void __launch_bounds__(BLOCK) triplet_fused_kernel(
    const int* __restrict__ labels,
    const f32x4* __restrict__ emb,    // [N][32]
    f32x4* __restrict__ out,          // [3][N][32]
    float* __restrict__ valid_out,    // [N]
    int N) {

    const int D4 = 32;
    int lane = threadIdx.x & 63;
    int i = blockIdx.x * (BLOCK >> 6) + (threadIdx.x >> 6);   // anchor (wave-uniform)
    if (i >= N) return;

    // Early independent loads: anchor label + anchor embedding row.
    int d4 = lane & 31;
    f32x4 ea = emb[(size_t)i * D4 + d4];   // row i (L1 broadcast across lanes)
    int my = labels[i];

    const int4* lab4 = (const int4*)labels;
    int nq = N >> 2;                       // N % 4 == 0

    int kb0 = (i + 1) >> 2;                // first chunk containing j > i

    // First-iteration validity mask: only lane 0's first chunk can hold j <= i.
    unsigned mv_first = 0xFFu;
    if (lane == 0) {
        int j0 = kb0 << 2;
        int nclr = i - j0 + 1;             // leading labels with j <= i (0..3)
        if (nclr > 0) mv_first &= (0xFFu << nclr);
    }

    int kbase = kb0;
    bool fp = false, fn = false;
    unsigned long long balp = 0, baln = 0;
    int basep = 0, basen = 0;
    unsigned msp = 0, msn = 0;             // captured masked match masks

    // 2-deep prefetch (clamped addresses; masked by mv in processing).
    int4 a0 = lab4[min(kbase + 2 * lane,     nq - 1)];
    int4 b0 = lab4[min(kbase + 2 * lane + 1, nq - 1)];
    int4 a1 = lab4[min(kbase + 128 + 2 * lane,     nq - 1)];
    int4 b1 = lab4[min(kbase + 128 + 2 * lane + 1, nq - 1)];

    unsigned mv_iter = mv_first;
    if (kbase < nq) {
        while (true) {
            int4 a2 = lab4[min(kbase + 256 + 2 * lane,     nq - 1)];
            int4 b2 = lab4[min(kbase + 256 + 2 * lane + 1, nq - 1)];

            int kq0 = kbase + 2 * lane, kq1 = kq0 + 1;
            unsigned mv = mv_iter;
            if (kq0 >= nq)      mv = 0;
            else if (kq1 >= nq) mv &= 0x0Fu;

            unsigned ms = (a0.x == my ?   1u : 0u) | (a0.y == my ?   2u : 0u)
                        | (a0.z == my ?   4u : 0u) | (a0.w == my ?   8u : 0u)
                        | (b0.x == my ?  16u : 0u) | (b0.y == my ?  32u : 0u)
                        | (b0.z == my ?  64u : 0u) | (b0.w == my ? 128u : 0u);

            unsigned mp = ms & mv;
            unsigned mn = (~ms) & mv;
            unsigned long long bp = __ballot(mp != 0u);
            unsigned long long bn = __ballot(mn != 0u);
            if (!fp && bp) { fp = true; balp = bp; basep = kbase; msp = mp; }
            if (!fn && bn) { fn = true; baln = bn; basen = kbase; msn = mn; }

            kbase += 128;
            if ((fp && fn) || kbase >= nq) break;
            a0 = a1; b0 = b1; a1 = a2; b1 = b2;
            mv_iter = 0xFFu;
        }
    }

    // Resolve exact indices: pure ALU + shfl (no memory on the chain).
    int p = 0, ng = 0;
    if (fp) {
        int ls = (int)__ffsll(balp) - 1;
        unsigned m = __shfl(msp, ls);
        p = ((basep + 2 * ls) << 2) + (__ffs(m) - 1);
    }
    if (fn) {
        int ls = (int)__ffsll(baln) - 1;
        unsigned m = __shfl(msn, ls);
        ng = ((basen + 2 * ls) << 2) + (__ffs(m) - 1);
    }

    float v = (fp && fn) ? 1.0f : 0.0f;

    // Combined gather: lanes<32 -> neg row, lanes>=32 -> pos row (one instr).
    size_t ND4 = (size_t)N * D4;
    int gsrc = (lane < 32) ? ng : p;
    f32x4 eg = emb[(size_t)gsrc * D4 + d4];

    if (lane == 0) valid_out[i] = v;

    // Pass 1: lanes<32 store anchor row (t=0), lanes>=32 store pos row (t=1).
    int   t  = lane >> 5;
    f32x4 r0 = (lane < 32) ? ea : eg;
    out[(size_t)t * ND4 + (size_t)i * D4 + d4] = r0 * v;

    // Pass 2: lanes<32 store neg row (t=2).
    if (lane < 32)
        out[2 * ND4 + (size_t)i * D4 + d4] = eg * v;
}

extern "C" void kernel_launch(void* const* d_in, const int* in_sizes, int n_in,
                              void* d_out, int out_size, void* d_ws, size_t ws_size,
                              hipStream_t stream) {
    const float* emb    = (const float*)d_in[0];
    const int*   labels = (const int*)d_in[1];   // harness passes integers as int32

    int N = in_sizes[1];             // 16384
    int D = in_sizes[0] / N;         // 128 (D4 = 32 hard-wired in kernel)

    float* out       = (float*)d_out;
    float* valid_out = out + (size_t)3 * N * D;  // tail of d_out: [N] valid mask

    int nblk = (N * 64 + BLOCK - 1) / BLOCK;     // one wave per anchor
    triplet_fused_kernel<<<nblk, BLOCK, 0, stream>>>(
        labels, (const f32x4*)emb, (f32x4*)out, valid_out, N);
}